// Round 28
// baseline (351.003 us; speedup 1.0000x reference)
//
#include <hip/hip_runtime.h>
#include <hip/hip_bf16.h>

namespace {

typedef __bf16 bf16x8 __attribute__((ext_vector_type(8)));
typedef float  f32x4  __attribute__((ext_vector_type(4)));
typedef unsigned short ushort8 __attribute__((ext_vector_type(8)));
typedef unsigned int u32;

constexpr int NTOK  = 3137;          // 1 + 16*196
constexpr int NH    = 8;
constexpr int DH    = 64;
constexpr int BH    = 64;            // BATCH*NH
constexpr int MROWS = 8 * NTOK;      // 25096
constexpr int NROWS = BH * NTOK;     // 200768 (rows of kb)
constexpr int MF    = 266;           // NB_FEATURES
constexpr int MPK   = 320;           // keymax padded m
constexpr int MC    = 288;           // ctx/QP logical m (18 frags)
constexpr int NMAXB = (NROWS + 255) / 256;  // 785 keymax blocks (4x64 rows)
constexpr int NCH   = 13;            // cls chunks of 256
constexpr int NBQKV = 197 * 12;      // 2364 k_qkv blocks
constexpr int NBOUT = 197 * 4;       // 788 k_out blocks

constexpr float DN     = 0.35355339059327379f;  // 64^-0.25
constexpr float HDN2   = 0.0625f;               // 0.5 * 64^-0.5
constexpr float RATIO  = 0.0613139368f;         // 266^-0.5
constexpr float EPSV   = 1.0e-4f;
constexpr float QSCALE = 0.125f;                // 64^-0.5

// XOR swizzles: 8-row spread; bijective within 64-col blocks (stride mult 64).
__device__ __forceinline__ int swz64(int r, int c)  { return (r << 6) + (c ^ ((r & 7) << 3)); }
__device__ __forceinline__ int swz320(int r, int c) { return r * 320 + (c ^ ((r & 7) << 3)); }

// bijective XCD-chunk swizzle (T1, m204 form): hardware bid -> logical lid
__device__ __forceinline__ int xcdchunk(int bid, int nb) {
  const int q = nb >> 3, r = nb & 7;
  const int xcd = bid & 7, slot = bid >> 3;
  return (xcd < r ? xcd * (q + 1) : r * (q + 1) + (xcd - r) * q) + slot;
}

__device__ __forceinline__ float b2f(unsigned short u) {
  union { unsigned int i; float f; } cv;
  cv.i = ((unsigned int)u) << 16;
  return cv.f;
}
__device__ __forceinline__ unsigned short f2b(float f) {
  __hip_bfloat16 h = __float2bfloat16(f);
  union { __hip_bfloat16 h; unsigned short u; } cv;
  cv.h = h;
  return cv.u;
}
__device__ __forceinline__ unsigned int pk2(float a, float b) {
  return (unsigned int)f2b(a) | ((unsigned int)f2b(b) << 16);
}
// monotone float<->uint order-preserving encoding (for atomicMax on floats)
__device__ __forceinline__ u32 fenc(float f) {
  u32 u = __float_as_uint(f);
  return (u & 0x80000000u) ? ~u : (u | 0x80000000u);
}
__device__ __forceinline__ float fdec(u32 u) {
  return __uint_as_float((u & 0x80000000u) ? (u ^ 0x80000000u) : ~u);
}
// async global->LDS, 16B per lane; LDS dest = wave-uniform base + lane*16
__device__ __forceinline__ void gload16(const void* g, void* l) {
  __builtin_amdgcn_global_load_lds(
      (const __attribute__((address_space(1))) u32*)g,
      (__attribute__((address_space(3))) u32*)l, 16, 0, 0);
}

// ---------- proj f32 -> bf16 in swizzled-image layout; init gmaxu -----------
__global__ __launch_bounds__(256) void k_projb(
    const float* __restrict__ proj, unsigned short* __restrict__ projb,
    u32* __restrict__ gmaxu)
{
  const int idx = (blockIdx.x * 256 + threadIdx.x) * 8;
  if (idx < MPK * 64) {
    const int m = idx >> 6, c0 = idx & 63;
    uint4 u;
    if (m < MF) {
      const float* src = proj + (size_t)m * 64 + c0;
      const float4 f0 = *(const float4*)src;
      const float4 f1 = *(const float4*)(src + 4);
      u.x = pk2(f0.x, f0.y); u.y = pk2(f0.z, f0.w);
      u.z = pk2(f1.x, f1.y); u.w = pk2(f1.z, f1.w);
    } else {
      u = uint4{0, 0, 0, 0};
    }
    *(uint4*)&projb[swz64(m, c0)] = u;
  }
  if (blockIdx.x == 0 && threadIdx.x == 0) *gmaxu = 0u;  // < enc of any finite
}

// ---------- elementwise fp32 -> bf16 (8 elems/thread) -----------------------
__global__ __launch_bounds__(256) void k_cvt(
    const float* __restrict__ src, unsigned short* __restrict__ dst, int n8)
{
  const int i = blockIdx.x * 256 + threadIdx.x;
  if (i < n8) {
    const float4 f0 = *(const float4*)(src + (size_t)i * 8);
    const float4 f1 = *(const float4*)(src + (size_t)i * 8 + 4);
    uint4 u;
    u.x = pk2(f0.x, f0.y); u.y = pk2(f0.z, f0.w);
    u.z = pk2(f1.x, f1.y); u.w = pk2(f1.z, f1.w);
    *(uint4*)(dst + (size_t)i * 8) = u;
  }
}

// ---------- transpose + fp32->bf16: dst[c][r] = bf16(src[r][c]) -------------
__global__ __launch_bounds__(256) void k_tconv(
    const float* __restrict__ src, unsigned short* __restrict__ dst,
    int R, int C)
{
  __shared__ float tile[64][65];
  const int cb = blockIdx.x * 64, rb = blockIdx.y * 64;
  const int tid = threadIdx.x;
  const int tr = tid >> 4, tc4 = (tid & 15) * 4;
  #pragma unroll
  for (int i = 0; i < 4; ++i) {
    const int r = tr + i * 16;
    const float4 f = *(const float4*)(src + (size_t)(rb + r) * C + cb + tc4);
    tile[r][tc4 + 0] = f.x; tile[r][tc4 + 1] = f.y;
    tile[r][tc4 + 2] = f.z; tile[r][tc4 + 3] = f.w;
  }
  __syncthreads();
  #pragma unroll
  for (int i = 0; i < 4; ++i) {
    const int wrow = tr + i * 16;
    uint2 u;
    u.x = pk2(tile[tc4 + 0][wrow], tile[tc4 + 1][wrow]);
    u.y = pk2(tile[tc4 + 2][wrow], tile[tc4 + 3][wrow]);
    *(uint2*)&dst[(size_t)(cb + wrow) * R + rb + tc4] = u;
  }
}

// ============ MFMA GEMM 1: qkv = xb(bf16) @ W_qkv, scatter q/k/v ============
__global__ __launch_bounds__(256) void k_qkv(
    const unsigned short* __restrict__ xb,  // bf16 [MROWS][512]
    const unsigned short* __restrict__ wT,  // bf16 [1536][512] (W^T)
    unsigned short* __restrict__ qb, unsigned short* __restrict__ kb,
    unsigned short* __restrict__ vb)
{
  __shared__ alignas(16) unsigned short As[128 * 64];  // [m][k] swz64 content
  __shared__ alignas(16) unsigned short Bs[128 * 64];  // [n][k] swz64 content
  const int lid = xcdchunk(blockIdx.x, NBQKV);
  const int bm = lid / 12, bn = lid % 12;
  const int tid = threadIdx.x;
  const int lane = tid & 63, wid = tid >> 6;
  const int wr = wid >> 1, wc = wid & 1;
  const int row0 = bm * 128, col0 = bn * 128;
  const int l15 = lane & 15, l4 = lane >> 4;
  const int lr = lane >> 3;                 // 0..7 (= r&7 for this lane)
  const int srcChunk = (lane & 7) ^ lr;     // inverse-swizzled source chunk

  const unsigned short* aRow[4];
  const unsigned short* bRow[4];
  #pragma unroll
  for (int j = 0; j < 4; ++j) {
    int gr = row0 + wid * 32 + j * 8 + lr;
    if (gr >= MROWS) gr = MROWS - 1;
    aRow[j] = xb + (size_t)gr * 512 + srcChunk * 8;
    bRow[j] = wT + (size_t)(col0 + wid * 32 + j * 8 + lr) * 512 + srcChunk * 8;
  }

  f32x4 acc[4][4];
  #pragma unroll
  for (int i = 0; i < 4; ++i)
    #pragma unroll
    for (int j = 0; j < 4; ++j) acc[i][j] = f32x4{0.f, 0.f, 0.f, 0.f};

  for (int kt = 0; kt < 512; kt += 64) {
    #pragma unroll
    for (int j = 0; j < 4; ++j) {
      gload16(aRow[j] + kt, &As[(wid * 32 + j * 8) * 64]);
      gload16(bRow[j] + kt, &Bs[(wid * 32 + j * 8) * 64]);
    }
    __syncthreads();
    #pragma unroll
    for (int ks = 0; ks < 2; ++ks) {
      bf16x8 af[4], bfr[4];
      #pragma unroll
      for (int i = 0; i < 4; ++i)
        af[i] = *(const bf16x8*)&As[swz64(wr * 64 + i * 16 + l15, ks * 32 + l4 * 8)];
      #pragma unroll
      for (int i = 0; i < 4; ++i)
        bfr[i] = *(const bf16x8*)&Bs[swz64(wc * 64 + i * 16 + l15, ks * 32 + l4 * 8)];
      #pragma unroll
      for (int mi = 0; mi < 4; ++mi)
        #pragma unroll
        for (int ni = 0; ni < 4; ++ni)
          acc[mi][ni] = __builtin_amdgcn_mfma_f32_16x16x32_bf16(
              af[mi], bfr[ni], acc[mi][ni], 0, 0, 0);
    }
    __syncthreads();
  }
  #pragma unroll
  for (int mi = 0; mi < 4; ++mi) {
    #pragma unroll
    for (int r = 0; r < 4; ++r) {
      const int grow = row0 + wr * 64 + mi * 16 + l4 * 4 + r;
      if (grow < MROWS) {
        const int bb = grow / NTOK, n = grow - bb * NTOK;
        #pragma unroll
        for (int ni = 0; ni < 4; ++ni) {
          const int gc = col0 + wc * 64 + ni * 16 + l15;
          const int which = gc >> 9;
          const int col = gc & 511;
          const int hh = col >> 6, d = col & 63;
          const size_t off = (size_t)((bb * NH + hh) * NTOK + n) * DH + d;
          const float vv = acc[mi][ni][r];
          if (which == 0)      qb[off] = f2b(vv * QSCALE);
          else if (which == 1) kb[off] = f2b(vv);
          else                 vb[off] = f2b(vv);
        }
      }
    }
  }
}

// ============ MFMA GEMM 2: out = attn(bf16) @ W_out -> fp32 =================
__global__ __launch_bounds__(256) void k_out(
    const unsigned short* __restrict__ a,    // bf16 [MROWS][512]
    const unsigned short* __restrict__ wT,   // bf16 [512][512] (W_out^T)
    float* __restrict__ out)                 // fp32 [MROWS][512]
{
  __shared__ alignas(16) unsigned short As[128 * 64];
  __shared__ alignas(16) unsigned short Bs[128 * 64];
  const int lid = xcdchunk(blockIdx.x, NBOUT);
  const int bm = lid / 4, bn = lid % 4;
  const int tid = threadIdx.x;
  const int lane = tid & 63, wid = tid >> 6;
  const int wr = wid >> 1, wc = wid & 1;
  const int row0 = bm * 128, col0 = bn * 128;
  const int l15 = lane & 15, l4 = lane >> 4;
  const int lr = lane >> 3;
  const int srcChunk = (lane & 7) ^ lr;

  const unsigned short* aRow[4];
  const unsigned short* bRow[4];
  #pragma unroll
  for (int j = 0; j < 4; ++j) {
    int gr = row0 + wid * 32 + j * 8 + lr;
    if (gr >= MROWS) gr = MROWS - 1;
    aRow[j] = a + (size_t)gr * 512 + srcChunk * 8;
    bRow[j] = wT + (size_t)(col0 + wid * 32 + j * 8 + lr) * 512 + srcChunk * 8;
  }

  f32x4 acc[4][4];
  #pragma unroll
  for (int i = 0; i < 4; ++i)
    #pragma unroll
    for (int j = 0; j < 4; ++j) acc[i][j] = f32x4{0.f, 0.f, 0.f, 0.f};

  for (int kt = 0; kt < 512; kt += 64) {
    #pragma unroll
    for (int j = 0; j < 4; ++j) {
      gload16(aRow[j] + kt, &As[(wid * 32 + j * 8) * 64]);
      gload16(bRow[j] + kt, &Bs[(wid * 32 + j * 8) * 64]);
    }
    __syncthreads();
    #pragma unroll
    for (int ks = 0; ks < 2; ++ks) {
      bf16x8 af[4], bfr[4];
      #pragma unroll
      for (int i = 0; i < 4; ++i)
        af[i] = *(const bf16x8*)&As[swz64(wr * 64 + i * 16 + l15, ks * 32 + l4 * 8)];
      #pragma unroll
      for (int i = 0; i < 4; ++i)
        bfr[i] = *(const bf16x8*)&Bs[swz64(wc * 64 + i * 16 + l15, ks * 32 + l4 * 8)];
      #pragma unroll
      for (int mi = 0; mi < 4; ++mi)
        #pragma unroll
        for (int ni = 0; ni < 4; ++ni)
          acc[mi][ni] = __builtin_amdgcn_mfma_f32_16x16x32_bf16(
              af[mi], bfr[ni], acc[mi][ni], 0, 0, 0);
    }
    __syncthreads();
  }
  #pragma unroll
  for (int mi = 0; mi < 4; ++mi) {
    #pragma unroll
    for (int r = 0; r < 4; ++r) {
      const int grow = row0 + wr * 64 + mi * 16 + l4 * 4 + r;
      if (grow < MROWS) {
        #pragma unroll
        for (int ni = 0; ni < 4; ++ni) {
          const int gc = col0 + wc * 64 + ni * 16 + l15;
          out[(size_t)grow * 512 + gc] = acc[mi][ni][r];
        }
      }
    }
  }
}

// ---------------- cls attention, parallel 3-stage ---------------------------
__global__ __launch_bounds__(256) void k_cls1(
    const unsigned short* __restrict__ qb, const unsigned short* __restrict__ kb,
    float* __restrict__ simb, float* __restrict__ cmax)
{
  __shared__ float qv[64];
  __shared__ float sred[4];
  const int bh = blockIdx.x, ch = blockIdx.y, tid = threadIdx.x;
  if (tid < 64) qv[tid] = b2f(qb[(size_t)bh * NTOK * 64 + tid]);
  __syncthreads();
  const int j = ch * 256 + tid;
  float dot = -3e38f;
  if (j < NTOK) {
    const unsigned short* kr = kb + (size_t)bh * NTOK * 64 + (size_t)j * 64;
    dot = 0.f;
    #pragma unroll
    for (int d0 = 0; d0 < 64; d0 += 8) {
      const bf16x8 kv = *(const bf16x8*)(kr + d0);
      #pragma unroll
      for (int j2 = 0; j2 < 8; ++j2) dot += qv[d0 + j2] * (float)kv[j2];
    }
    simb[bh * 3200 + j] = dot;
  }
  float lm = dot;
  #pragma unroll
  for (int off = 32; off; off >>= 1) lm = fmaxf(lm, __shfl_xor(lm, off));
  if ((tid & 63) == 0) sred[tid >> 6] = lm;
  __syncthreads();
  if (tid == 0)
    cmax[bh * NCH + ch] = fmaxf(fmaxf(sred[0], sred[1]), fmaxf(sred[2], sred[3]));
}

__global__ __launch_bounds__(256) void k_cls2(
    const unsigned short* __restrict__ vb, const float* __restrict__ simb,
    const float* __restrict__ cmax, float* __restrict__ pacc,
    float* __restrict__ psum)
{
  __shared__ float pa[4][64];
  __shared__ float pw[4];
  const int bh = blockIdx.x, ch = blockIdx.y, tid = threadIdx.x;
  const int wave = tid >> 6, d = tid & 63;
  float mx = -3e38f;
  #pragma unroll
  for (int i = 0; i < NCH; ++i) mx = fmaxf(mx, cmax[bh * NCH + i]);
  float acc = 0.f, ps = 0.f;
  const int j0 = ch * 256 + wave * 64;
  for (int i = 0; i < 64; ++i) {
    const int j = j0 + i;
    if (j < NTOK) {
      const float p = __expf(simb[bh * 3200 + j] - mx);
      acc += p * b2f(vb[(size_t)bh * NTOK * 64 + (size_t)j * 64 + d]);
      ps += p;
    }
  }
  pa[wave][d] = acc;
  if (d == 0) pw[wave] = ps;
  __syncthreads();
  if (tid < 64)
    pacc[((size_t)bh * NCH + ch) * 64 + tid] = pa[0][tid] + pa[1][tid] + pa[2][tid] + pa[3][tid];
  if (tid == 0)
    psum[bh * NCH + ch] = pw[0] + pw[1] + pw[2] + pw[3];
}

__global__ __launch_bounds__(64) void k_cls3(
    const float* __restrict__ pacc, const float* __restrict__ psum,
    unsigned short* __restrict__ attnb)
{
  const int bh = blockIdx.x, d = threadIdx.x;
  float a = 0.f, s = 0.f;
  #pragma unroll
  for (int ch = 0; ch < NCH; ++ch) {
    a += pacc[((size_t)bh * NCH + ch) * 64 + d];
    s += psum[bh * NCH + ch];
  }
  const int bb = bh >> 3, hh = bh & 7;
  attnb[((size_t)bb * NTOK + 0) * 512 + hh * 64 + d] = f2b(a / s);
}

// -------- MFMA global key-projection max (4x64 rows/block, atomic) ----------
__global__ __launch_bounds__(256) void k_keymax(
    const unsigned short* __restrict__ kb, const unsigned short* __restrict__ projb,
    u32* __restrict__ gmaxu)
{
  __shared__ alignas(16) unsigned short projL[MPK * 64];
  __shared__ float red[4];
  const int blk = blockIdx.x, tid = threadIdx.x;
  const int lane = tid & 63, wave = tid >> 6;
  const int l15 = lane & 15, l4 = lane >> 4;
  const int mw0 = wave * 80;
  {
    const char* srcb = (const char*)projb;
    char* dstb = (char*)projL;
    #pragma unroll
    for (int j = 0; j < 10; ++j) {
      const int off = (j * 4 + wave) * 1024;
      gload16(srcb + off + lane * 16, dstb + off);
    }
  }
  __syncthreads();
  float lm = -3e38f;
  for (int rg = 0; rg < 4; ++rg) {
    const int row0 = (blk * 4 + rg) * 64;
    if (row0 >= NROWS) break;
    bf16x8 bfrag[4][2];
    #pragma unroll
    for (int tf = 0; tf < 4; ++tf) {
      int gr = row0 + tf * 16 + l15;
      if (gr >= NROWS) gr = NROWS - 1;
      #pragma unroll
      for (int ks = 0; ks < 2; ++ks)
        bfrag[tf][ks] = *(const bf16x8*)(kb + (size_t)gr * 64 + ks * 32 + l4 * 8);
    }
    f32x4 acc[5][4];
    #pragma unroll
    for (int i = 0; i < 5; ++i)
      #pragma unroll
      for (int j = 0; j < 4; ++j) acc[i][j] = f32x4{0.f, 0.f, 0.f, 0.f};
    #pragma unroll
    for (int mf = 0; mf < 5; ++mf) {
      const bf16x8 a0 = *(const bf16x8*)&projL[swz64(mw0 + mf * 16 + l15, l4 * 8)];
      const bf16x8 a1 = *(const bf16x8*)&projL[swz64(mw0 + mf * 16 + l15, 32 + l4 * 8)];
      #pragma unroll
      for (int tf = 0; tf < 4; ++tf) {
        acc[mf][tf] = __builtin_amdgcn_mfma_f32_16x16x32_bf16(a0, bfrag[tf][0], acc[mf][tf], 0, 0, 0);
        acc[mf][tf] = __builtin_amdgcn_mfma_f32_16x16x32_bf16(a1, bfrag[tf][1], acc[mf][tf], 0, 0, 0);
      }
    }
    #pragma unroll
    for (int tf = 0; tf < 4; ++tf) {
      const bool colok = (row0 + tf * 16 + l15) < NROWS;
      #pragma unroll
      for (int mf = 0; mf < 5; ++mf)
        #pragma unroll
        for (int r = 0; r < 4; ++r) {
          const int m = mw0 + mf * 16 + l4 * 4 + r;
          if (colok && m < MF) lm = fmaxf(lm, DN * acc[mf][tf][r]);
        }
    }
  }
  #pragma unroll
  for (int off = 32; off; off >>= 1) lm = fmaxf(lm, __shfl_xor(lm, off));
  if (lane == 0) red[wave] = lm;
  __syncthreads();
  if (tid == 0) {
    const float bm = fmaxf(fmaxf(red[0], red[1]), fmaxf(red[2], red[3]));
    atomicMax(gmaxu, fenc(bm));
  }
}

// ======== fused linear attention: ctx phase + qry phase, one block/group ====
// r28: + K-fragment register prefetch (named kA/kB ping-pong) so tile kt+1's
// global K loads issue before computef(kt)'s MFMA chain (T14 mechanism);
// + diag parallelized across all 8 waves (1 load/lane + shfl_xor tree) in
// both phases.  Everything else identical to r27.
__global__ __launch_bounds__(512) void k_lin(
    const unsigned short* __restrict__ kb, const unsigned short* __restrict__ vb,
    const unsigned short* __restrict__ qb, const unsigned short* __restrict__ projb,
    const u32* __restrict__ gmaxu, unsigned short* __restrict__ attnb)
{
  __shared__ alignas(16) unsigned short smAB[2 * 64 * 320];  // 80 KB aliased region
  __shared__ alignas(16) unsigned short ctxL[64 * 320];      // 40 KB ctx swz320 image
  __shared__ float diagA[2][64];
  __shared__ float diagB[2][64];
  __shared__ float rmax_l[2][8][64];
  __shared__ float dnm_l[2][8][64];

  unsigned short* const kpT = smAB;                   // [MC*64] swz64
  unsigned short* const vTb = smAB + MC * 64;         // [2][64*64] swz64 dbuf

  const int g = blockIdx.x, bh = g >> 4, c = g & 15;
  const int bb = bh >> 3, hh = bh & 7;
  const int tid = threadIdx.x;
  const int lane = tid & 63, wave = tid >> 6;
  const int l15 = lane & 15, l4 = lane >> 4;
  const int nf = (wave < 2) ? 3 : 2;
  const int M0 = (wave < 2) ? wave * 48 : 96 + (wave - 2) * 32;
  const float gm = fdec(*gmaxu);

  bf16x8 pfr[3][2];  // shared by both phases (same wave->m mapping)
  #pragma unroll
  for (int mf = 0; mf < 3; ++mf)
    #pragma unroll
    for (int ks = 0; ks < 2; ++ks)
      pfr[mf][ks] = (mf < nf)
          ? *(const bf16x8*)&projb[swz64(M0 + mf * 16 + l15, ks * 32 + l4 * 8)]
          : bf16x8{0, 0, 0, 0, 0, 0, 0, 0};

  const unsigned short* ksrc = kb + (size_t)bh * NTOK * 64;
  const unsigned short* vsrc = vb + (size_t)bh * NTOK * 64;
  const unsigned short* qsrc = qb + (size_t)bh * NTOK * 64;

  // ===================== phase A: context =====================
  f32x4 ctxacc[3][4];
  #pragma unroll
  for (int i = 0; i < 3; ++i)
    #pragma unroll
    for (int j = 0; j < 4; ++j) ctxacc[i][j] = f32x4{0.f, 0.f, 0.f, 0.f};
  float ksump[3][4];
  #pragma unroll
  for (int i = 0; i < 3; ++i)
    #pragma unroll
    for (int j = 0; j < 4; ++j) ksump[i][j] = 0.f;

  // preload K fragments for tile kt (8 x bf16x8 = 32 VGPR)
  auto kloadf = [&](int kt, bf16x8 (&kfr)[4][2]) {
    #pragma unroll
    for (int tf = 0; tf < 4; ++tf) {
      const int n = kt * 64 + tf * 16 + l15;
      const int nn = (n < 197) ? n : 0;
      const int node = (nn == 0) ? 0 : 1 + c * 196 + (nn - 1);
      kfr[tf][0] = *(const bf16x8*)(ksrc + (size_t)node * 64 + l4 * 8);
      kfr[tf][1] = *(const bf16x8*)(ksrc + (size_t)node * 64 + 32 + l4 * 8);
    }
  };
  auto stagevd = [&](int kt, int buf) {
    {  // vT staging (all threads)
      const int t = tid & 63, dblk = (tid >> 6) & 7;
      const int n = kt * 64 + t;
      unsigned short* vT = vTb + buf * 4096;
      if (n < 197) {
        const int node = (n == 0) ? 0 : 1 + c * 196 + (n - 1);
        const ushort8 v = *(const ushort8*)(vsrc + (size_t)node * 64 + dblk * 8);
        #pragma unroll
        for (int j = 0; j < 8; ++j) vT[swz64(dblk * 8 + j, t)] = v[j];
      } else {
        #pragma unroll
        for (int j = 0; j < 8; ++j) vT[swz64(dblk * 8 + j, t)] = 0;
      }
    }
    {  // diag parallel: wave w rows 8w..8w+7, lane chunk lane&7
      const int row = wave * 8 + (lane >> 3);
      const int n = kt * 64 + row;
      const int nn = (n < 197) ? n : 0;
      const int node = (nn == 0) ? 0 : 1 + c * 196 + (nn - 1);
      const bf16x8 v = *(const bf16x8*)(ksrc + (size_t)node * 64 + (lane & 7) * 8);
      float s = 0.f;
      #pragma unroll
      for (int j = 0; j < 8; ++j) { const float f = (float)v[j]; s += f * f; }
      s += __shfl_xor(s, 1); s += __shfl_xor(s, 2); s += __shfl_xor(s, 4);
      if ((lane & 7) == 0) diagA[buf][row] = HDN2 * s;
    }
  };
  // stage1 + stage2 for tile kt reading buffer buf, K from preloaded kfr
  auto computef = [&](int kt, int buf, const bf16x8 (&kfr)[4][2]) {
    #pragma unroll
    for (int tf = 0; tf < 4; ++tf) {
      f32x4 a1[3];
      #pragma unroll
      for (int mf = 0; mf < 3; ++mf) {
        a1[mf] = f32x4{0.f, 0.f, 0.f, 0.f};
        if (mf < nf) {
          a1[mf] = __builtin_amdgcn_mfma_f32_16x16x32_bf16(pfr[mf][0], kfr[tf][0], a1[mf], 0, 0, 0);
          a1[mf] = __builtin_amdgcn_mfma_f32_16x16x32_bf16(pfr[mf][1], kfr[tf][1], a1[mf], 0, 0, 0);
        }
      }
      const int t = tf * 16 + l15;
      const int nv = kt * 64 + t;
      const float dg = diagA[buf][t];
      #pragma unroll
      for (int mf = 0; mf < 3; ++mf) {
        if (mf < nf) {
          #pragma unroll
          for (int r = 0; r < 4; ++r) {
            const int m = M0 + mf * 16 + l4 * 4 + r;
            float kp = 0.f;
            if (m < MF && nv < 197)
              kp = RATIO * (__expf(DN * a1[mf][r] - dg - gm) + EPSV);
            ksump[mf][r] += kp;
            kpT[swz64(m, t)] = f2b(kp);
          }
        }
      }
    }
    // stage 2: ctx += KP_T . vT (intra-wave kpT dependency only)
    #pragma unroll
    for (int ks = 0; ks < 2; ++ks) {
      bf16x8 a2[3];
      #pragma unroll
      for (int mf = 0; mf < 3; ++mf)
        if (mf < nf)
          a2[mf] = *(const bf16x8*)&kpT[swz64(M0 + mf * 16 + l15, ks * 32 + l4 * 8)];
      const unsigned short* vT = vTb + buf * 4096;
      #pragma unroll
      for (int df = 0; df < 4; ++df) {
        const bf16x8 b2 = *(const bf16x8*)&vT[swz64(df * 16 + l15, ks * 32 + l4 * 8)];
        #pragma unroll
        for (int mf = 0; mf < 3; ++mf)
          if (mf < nf)
            ctxacc[mf][df] = __builtin_amdgcn_mfma_f32_16x16x32_bf16(a2[mf], b2, ctxacc[mf][df], 0, 0, 0);
      }
    }
  };

  // fully-unrolled pipelined schedule (named kA/kB ping-pong, rule #20)
  bf16x8 kA[4][2], kB[4][2];
  kloadf(0, kA);
  stagevd(0, 0);
  __syncthreads();
  stagevd(1, 1); kloadf(1, kB);   // issue next-tile loads before MFMA chain
  computef(0, 0, kA);
  __syncthreads();
  stagevd(2, 0); kloadf(2, kA);
  computef(1, 1, kB);
  __syncthreads();
  stagevd(3, 1); kloadf(3, kB);
  computef(2, 0, kA);
  __syncthreads();
  computef(3, 1, kB);
  __syncthreads();

  // ksum butterfly: after 4 xor steps ALL lanes in the l15-group hold the sum;
  // (wave,l4,r)->m mapping matches phase B's ksr exactly -> registers only.
  float ksr[3][4];
  #pragma unroll
  for (int mf = 0; mf < 3; ++mf) {
    #pragma unroll
    for (int r = 0; r < 4; ++r) {
      float v = ksump[mf][r];
      v += __shfl_xor(v, 1); v += __shfl_xor(v, 2);
      v += __shfl_xor(v, 4); v += __shfl_xor(v, 8);
      ksr[mf][r] = v;
    }
  }
  // ctx -> ctxL (same swz320 image layout the global write used)
  #pragma unroll
  for (int mf = 0; mf < 3; ++mf) {
    if (mf < nf) {
      #pragma unroll
      for (int df = 0; df < 4; ++df) {
        const int d = df * 16 + l15;
        const int m = M0 + mf * 16 + l4 * 4;
        uint2 u;
        u.x = pk2(ctxacc[mf][df][0], ctxacc[mf][df][1]);
        u.y = pk2(ctxacc[mf][df][2], ctxacc[mf][df][3]);
        *(uint2*)&ctxL[swz320(d, m)] = u;
      }
    }
  }
  __syncthreads();   // ctxL visible; all phase-A LDS reads complete

  // ===================== phase B: query (r23 schedule) =====================
  const int tf4 = wave & 3, dfh = wave >> 2;

  auto diagf = [&](int qt, int buf) {
    // diag parallel: wave w rows 8w..8w+7, lane chunk lane&7
    const int row = wave * 8 + (lane >> 3);
    const int n = qt * 64 + row;
    const int nn = (n < 196) ? n : 0;
    const int node = 1 + c * 196 + nn;
    const bf16x8 v = *(const bf16x8*)(qsrc + (size_t)node * 64 + (lane & 7) * 8);
    float s = 0.f;
    #pragma unroll
    for (int j = 0; j < 8; ++j) { const float f = (float)v[j]; s += f * f; }
    s += __shfl_xor(s, 1); s += __shfl_xor(s, 2); s += __shfl_xor(s, 4);
    if ((lane & 7) == 0) diagB[buf][row] = HDN2 * s;
  };
  auto stage3f = [&](int qt, int buf, f32x4 (&acc3)[3][4]) {
    #pragma unroll
    for (int i = 0; i < 3; ++i)
      #pragma unroll
      for (int j = 0; j < 4; ++j) acc3[i][j] = f32x4{0.f, 0.f, 0.f, 0.f};
    #pragma unroll
    for (int tf = 0; tf < 4; ++tf) {
      const int n = qt * 64 + tf * 16 + l15;
      const int nn = (n < 196) ? n : 0;
      const int node = 1 + c * 196 + nn;
      bf16x8 b0 = *(const bf16x8*)(qsrc + (size_t)node * 64 + l4 * 8);
      bf16x8 b1 = *(const bf16x8*)(qsrc + (size_t)node * 64 + 32 + l4 * 8);
      #pragma unroll
      for (int mf = 0; mf < 3; ++mf) {
        if (mf < nf) {
          acc3[mf][tf] = __builtin_amdgcn_mfma_f32_16x16x32_bf16(pfr[mf][0], b0, acc3[mf][tf], 0, 0, 0);
          acc3[mf][tf] = __builtin_amdgcn_mfma_f32_16x16x32_bf16(pfr[mf][1], b1, acc3[mf][tf], 0, 0, 0);
        }
      }
    }
    #pragma unroll
    for (int tf = 0; tf < 4; ++tf) {
      float v = -3e38f;
      #pragma unroll
      for (int mf = 0; mf < 3; ++mf)
        if (mf < nf)
          #pragma unroll
          for (int r = 0; r < 4; ++r) {
            const int m = M0 + mf * 16 + l4 * 4 + r;
            if (m < MF) v = fmaxf(v, DN * acc3[mf][tf][r]);
          }
      v = fmaxf(v, __shfl_xor(v, 16));
      v = fmaxf(v, __shfl_xor(v, 32));
      if (l4 == 0) rmax_l[buf][wave][tf * 16 + l15] = v;
    }
  };
  auto qpwritef = [&](int qt, int buf, const f32x4 (&acc3)[3][4]) {
    unsigned short* qp = smAB + buf * (64 * 320);
    #pragma unroll
    for (int tf = 0; tf < 4; ++tf) {
      const int t = tf * 16 + l15;
      const int tq = qt * 64 + t;
      float rm = fmaxf(fmaxf(rmax_l[buf][0][t], rmax_l[buf][1][t]),
                       fmaxf(rmax_l[buf][2][t], rmax_l[buf][3][t]));
      rm = fmaxf(rm, fmaxf(fmaxf(rmax_l[buf][4][t], rmax_l[buf][5][t]),
                           fmaxf(rmax_l[buf][6][t], rmax_l[buf][7][t])));
      const float dg = diagB[buf][t];
      float dpart = 0.f;
      #pragma unroll
      for (int mf = 0; mf < 3; ++mf) {
        if (mf < nf) {
          float e[4];
          #pragma unroll
          for (int r = 0; r < 4; ++r) {
            const int m = M0 + mf * 16 + l4 * 4 + r;
            e[r] = (m < MF && tq < 196)
                 ? RATIO * (__expf(DN * acc3[mf][tf][r] - dg - rm) + EPSV) : 0.f;
            dpart += e[r] * ksr[mf][r];
          }
          uint2 u; u.x = pk2(e[0], e[1]); u.y = pk2(e[2], e[3]);
          *(uint2*)&qp[swz320(t, M0 + mf * 16 + l4 * 4)] = u;
        }
      }
      dpart += __shfl_xor(dpart, 16);
      dpart += __shfl_xor(dpart, 32);
      if (l4 == 0) dnm_l[buf][wave][t] = dpart;
    }
  };
  auto stage4f = [&](int qt, int buf) {
    const unsigned short* qp = smAB + buf * (64 * 320);
    f32x4 oacc[2];
    oacc[0] = f32x4{0.f, 0.f, 0.f, 0.f};
    oacc[1] = f32x4{0.f, 0.f, 0.f, 0.f};
    #pragma unroll
    for (int ks = 0; ks < 9; ++ks) {
      const bf16x8 a4 = *(const bf16x8*)&qp[swz320(tf4 * 16 + l15, ks * 32 + l4 * 8)];
      #pragma unroll
      for (int di = 0; di < 2; ++di) {
        const int d = dfh * 32 + di * 16 + l15;
        const bf16x8 b4 = *(const bf16x8*)&ctxL[swz320(d, ks * 32 + l4 * 8)];
        oacc[di] = __builtin_amdgcn_mfma_f32_16x16x32_bf16(a4, b4, oacc[di], 0, 0, 0);
      }
    }
    #pragma unroll
    for (int r = 0; r < 4; ++r) {
      const int tl = tf4 * 16 + l4 * 4 + r;
      const int tq = qt * 64 + tl;
      if (tq < 196) {
        float denom = 0.f;
        #pragma unroll
        for (int w8 = 0; w8 < 8; ++w8) denom += dnm_l[buf][w8][tl];
        const float dinv = 1.0f / denom;
        const int node = 1 + c * 196 + tq;
        unsigned short* orow = attnb + ((size_t)bb * NTOK + node) * 512 + hh * 64 + dfh * 32;
        #pragma unroll
        for (int di = 0; di < 2; ++di)
          orow[di * 16 + l15] = f2b(oacc[di][r] * dinv);
      }
    }
  };

  f32x4 acc3[3][4];
  diagf(0, 0);
  stage3f(0, 0, acc3);
  __syncthreads();             // rmax(0)+diag(0) visible
  qpwritef(0, 0, acc3);        // first qp write: >=2 barriers after last kpT/vT read
  for (int qt = 1; qt < 4; ++qt) {
    const int b = qt & 1, pb = b ^ 1;
    __syncthreads();           // qp(qt-1)+dnm(qt-1) visible
    diagf(qt, b);
    stage4f(qt - 1, pb);       // reads qp[pb]/dnm[pb]/ctxL
    stage3f(qt, b, acc3);      // writes rmax[b]
    __syncthreads();           // rmax(qt)+diag(qt) visible; stage4 reads done
    qpwritef(qt, b, acc3);     // writes qp[b]/dnm[b]
  }
  __syncthreads();             // qp(3)+dnm(3) visible
  stage4f(3, 1);
}

}  // namespace

extern "C" void kernel_launch(void* const* d_in, const int* in_sizes, int n_in,
                              void* d_out, int out_size, void* d_ws, size_t ws_size,
                              hipStream_t stream) {
  (void)in_sizes; (void)n_in; (void)out_size; (void)ws_size;
  const float* x    = (const float*)d_in[0];
  const float* wqkv = (const float*)d_in[1];
  const float* wout = (const float*)d_in[2];
  const float* proj = (const float*)d_in[3];
  float* out = (float*)d_out;

  const size_t QKV = (size_t)BH * NTOK * DH;  // 12,849,152 elements
  unsigned short* qb    = (unsigned short*)d_ws;
  unsigned short* kb    = qb + QKV;
  unsigned short* vb    = kb + QKV;
  unsigned short* attnb = vb + QKV;
  float* fbase = (float*)(attnb + QKV);
  u32*   gmaxu = (u32*)(fbase + 4096);        // 1 (encoded float)
  float* simb = fbase + 8192;                 // 64*3200
  float* cmax = simb + 64 * 3200;             // 64*13 (padded 1024)
  float* pacc = cmax + 1024;                  // 64*13*64
  float* psum = pacc + 64 * NCH * 64;         // 64*13 (padded 1024)
  unsigned short* wqkvT = (unsigned short*)(psum + 1024);  // bf16 [1536][512]
  unsigned short* woutT = wqkvT + 1536 * 512;              // bf16 [512][512]
  unsigned short* projb = woutT + 512 * 512;               // bf16 [320][64] swz image
  unsigned short* xb = attnb;  // xb aliases attnb (dead before attnb writes)

  const dim3 blk(256);
  k_projb  <<<dim3(10),       blk, 0, stream>>>(proj, projb, gmaxu);
  k_tconv  <<<dim3(24, 8),    blk, 0, stream>>>(wqkv, wqkvT, 512, 1536);
  k_tconv  <<<dim3(8, 8),     blk, 0, stream>>>(wout, woutT, 512, 512);
  k_cvt    <<<dim3((int)(QKV / 8 + 255) / 256), blk, 0, stream>>>(x, xb, (int)(QKV / 8));
  k_qkv    <<<dim3(NBQKV),    blk, 0, stream>>>(xb, wqkvT, qb, kb, vb);
  k_cls1   <<<dim3(BH, NCH),  blk, 0, stream>>>(qb, kb, simb, cmax);
  k_cls2   <<<dim3(BH, NCH),  blk, 0, stream>>>(vb, simb, cmax, pacc, psum);
  k_cls3   <<<dim3(BH), dim3(64), 0, stream>>>(pacc, psum, attnb);
  k_keymax <<<dim3(NMAXB),    blk, 0, stream>>>(kb, projb, gmaxu);
  k_lin    <<<dim3(1024), dim3(512), 0, stream>>>(kb, vb, qb, projb, gmaxu, attnb);
  k_out    <<<dim3(NBOUT),    blk, 0, stream>>>(attnb, woutT, out);
}

// Round 29
// 320.061 us; speedup vs baseline: 1.0967x; 1.0967x over previous
//
#include <hip/hip_runtime.h>
#include <hip/hip_bf16.h>

namespace {

typedef __bf16 bf16x8 __attribute__((ext_vector_type(8)));
typedef float  f32x4  __attribute__((ext_vector_type(4)));
typedef unsigned short ushort8 __attribute__((ext_vector_type(8)));
typedef unsigned int u32;

constexpr int NTOK  = 3137;          // 1 + 16*196
constexpr int NH    = 8;
constexpr int DH    = 64;
constexpr int BH    = 64;            // BATCH*NH
constexpr int MROWS = 8 * NTOK;      // 25096
constexpr int NROWS = BH * NTOK;     // 200768 (rows of kb)
constexpr int MF    = 266;           // NB_FEATURES
constexpr int MPK   = 320;           // keymax padded m
constexpr int MC    = 288;           // ctx/QP logical m (18 frags)
constexpr int NMAXB = (NROWS + 255) / 256;  // 785 keymax blocks (4x64 rows)
constexpr int NCH   = 13;            // cls chunks of 256
constexpr int NBQKV = 197 * 12;      // 2364 k_qkv blocks
constexpr int NBOUT = 197 * 4;       // 788 k_out blocks

constexpr float DN     = 0.35355339059327379f;  // 64^-0.25
constexpr float HDN2   = 0.0625f;               // 0.5 * 64^-0.5
constexpr float RATIO  = 0.0613139368f;         // 266^-0.5
constexpr float EPSV   = 1.0e-4f;
constexpr float QSCALE = 0.125f;                // 64^-0.5

// XOR swizzles: 8-row spread; bijective within 64-col blocks (stride mult 64).
__device__ __forceinline__ int swz64(int r, int c)  { return (r << 6) + (c ^ ((r & 7) << 3)); }
__device__ __forceinline__ int swz320(int r, int c) { return r * 320 + (c ^ ((r & 7) << 3)); }

// bijective XCD-chunk swizzle (T1, m204 form): hardware bid -> logical lid
__device__ __forceinline__ int xcdchunk(int bid, int nb) {
  const int q = nb >> 3, r = nb & 7;
  const int xcd = bid & 7, slot = bid >> 3;
  return (xcd < r ? xcd * (q + 1) : r * (q + 1) + (xcd - r) * q) + slot;
}

__device__ __forceinline__ float b2f(unsigned short u) {
  union { unsigned int i; float f; } cv;
  cv.i = ((unsigned int)u) << 16;
  return cv.f;
}
__device__ __forceinline__ unsigned short f2b(float f) {
  __hip_bfloat16 h = __float2bfloat16(f);
  union { __hip_bfloat16 h; unsigned short u; } cv;
  cv.h = h;
  return cv.u;
}
__device__ __forceinline__ unsigned int pk2(float a, float b) {
  return (unsigned int)f2b(a) | ((unsigned int)f2b(b) << 16);
}
// monotone float<->uint order-preserving encoding (for atomicMax on floats)
__device__ __forceinline__ u32 fenc(float f) {
  u32 u = __float_as_uint(f);
  return (u & 0x80000000u) ? ~u : (u | 0x80000000u);
}
__device__ __forceinline__ float fdec(u32 u) {
  return __uint_as_float((u & 0x80000000u) ? (u ^ 0x80000000u) : ~u);
}
// async global->LDS, 16B per lane; LDS dest = wave-uniform base + lane*16
__device__ __forceinline__ void gload16(const void* g, void* l) {
  __builtin_amdgcn_global_load_lds(
      (const __attribute__((address_space(1))) u32*)g,
      (__attribute__((address_space(3))) u32*)l, 16, 0, 0);
}

// ---------- proj f32 -> bf16 in swizzled-image layout; init gmaxu -----------
__global__ __launch_bounds__(256) void k_projb(
    const float* __restrict__ proj, unsigned short* __restrict__ projb,
    u32* __restrict__ gmaxu)
{
  const int idx = (blockIdx.x * 256 + threadIdx.x) * 8;
  if (idx < MPK * 64) {
    const int m = idx >> 6, c0 = idx & 63;
    uint4 u;
    if (m < MF) {
      const float* src = proj + (size_t)m * 64 + c0;
      const float4 f0 = *(const float4*)src;
      const float4 f1 = *(const float4*)(src + 4);
      u.x = pk2(f0.x, f0.y); u.y = pk2(f0.z, f0.w);
      u.z = pk2(f1.x, f1.y); u.w = pk2(f1.z, f1.w);
    } else {
      u = uint4{0, 0, 0, 0};
    }
    *(uint4*)&projb[swz64(m, c0)] = u;
  }
  if (blockIdx.x == 0 && threadIdx.x == 0) *gmaxu = 0u;  // < enc of any finite
}

// ---------- elementwise fp32 -> bf16 (8 elems/thread) -----------------------
__global__ __launch_bounds__(256) void k_cvt(
    const float* __restrict__ src, unsigned short* __restrict__ dst, int n8)
{
  const int i = blockIdx.x * 256 + threadIdx.x;
  if (i < n8) {
    const float4 f0 = *(const float4*)(src + (size_t)i * 8);
    const float4 f1 = *(const float4*)(src + (size_t)i * 8 + 4);
    uint4 u;
    u.x = pk2(f0.x, f0.y); u.y = pk2(f0.z, f0.w);
    u.z = pk2(f1.x, f1.y); u.w = pk2(f1.z, f1.w);
    *(uint4*)(dst + (size_t)i * 8) = u;
  }
}

// ---------- transpose + fp32->bf16: dst[c][r] = bf16(src[r][c]) -------------
__global__ __launch_bounds__(256) void k_tconv(
    const float* __restrict__ src, unsigned short* __restrict__ dst,
    int R, int C)
{
  __shared__ float tile[64][65];
  const int cb = blockIdx.x * 64, rb = blockIdx.y * 64;
  const int tid = threadIdx.x;
  const int tr = tid >> 4, tc4 = (tid & 15) * 4;
  #pragma unroll
  for (int i = 0; i < 4; ++i) {
    const int r = tr + i * 16;
    const float4 f = *(const float4*)(src + (size_t)(rb + r) * C + cb + tc4);
    tile[r][tc4 + 0] = f.x; tile[r][tc4 + 1] = f.y;
    tile[r][tc4 + 2] = f.z; tile[r][tc4 + 3] = f.w;
  }
  __syncthreads();
  #pragma unroll
  for (int i = 0; i < 4; ++i) {
    const int wrow = tr + i * 16;
    uint2 u;
    u.x = pk2(tile[tc4 + 0][wrow], tile[tc4 + 1][wrow]);
    u.y = pk2(tile[tc4 + 2][wrow], tile[tc4 + 3][wrow]);
    *(uint2*)&dst[(size_t)(cb + wrow) * R + rb + tc4] = u;
  }
}

// ============ MFMA GEMM 1: qkv = xb(bf16) @ W_qkv, scatter q/k/v ============
__global__ __launch_bounds__(256) void k_qkv(
    const unsigned short* __restrict__ xb,  // bf16 [MROWS][512]
    const unsigned short* __restrict__ wT,  // bf16 [1536][512] (W^T)
    unsigned short* __restrict__ qb, unsigned short* __restrict__ kb,
    unsigned short* __restrict__ vb)
{
  __shared__ alignas(16) unsigned short As[128 * 64];  // [m][k] swz64 content
  __shared__ alignas(16) unsigned short Bs[128 * 64];  // [n][k] swz64 content
  const int lid = xcdchunk(blockIdx.x, NBQKV);
  const int bm = lid / 12, bn = lid % 12;
  const int tid = threadIdx.x;
  const int lane = tid & 63, wid = tid >> 6;
  const int wr = wid >> 1, wc = wid & 1;
  const int row0 = bm * 128, col0 = bn * 128;
  const int l15 = lane & 15, l4 = lane >> 4;
  const int lr = lane >> 3;                 // 0..7 (= r&7 for this lane)
  const int srcChunk = (lane & 7) ^ lr;     // inverse-swizzled source chunk

  const unsigned short* aRow[4];
  const unsigned short* bRow[4];
  #pragma unroll
  for (int j = 0; j < 4; ++j) {
    int gr = row0 + wid * 32 + j * 8 + lr;
    if (gr >= MROWS) gr = MROWS - 1;
    aRow[j] = xb + (size_t)gr * 512 + srcChunk * 8;
    bRow[j] = wT + (size_t)(col0 + wid * 32 + j * 8 + lr) * 512 + srcChunk * 8;
  }

  f32x4 acc[4][4];
  #pragma unroll
  for (int i = 0; i < 4; ++i)
    #pragma unroll
    for (int j = 0; j < 4; ++j) acc[i][j] = f32x4{0.f, 0.f, 0.f, 0.f};

  for (int kt = 0; kt < 512; kt += 64) {
    #pragma unroll
    for (int j = 0; j < 4; ++j) {
      gload16(aRow[j] + kt, &As[(wid * 32 + j * 8) * 64]);
      gload16(bRow[j] + kt, &Bs[(wid * 32 + j * 8) * 64]);
    }
    __syncthreads();
    #pragma unroll
    for (int ks = 0; ks < 2; ++ks) {
      bf16x8 af[4], bfr[4];
      #pragma unroll
      for (int i = 0; i < 4; ++i)
        af[i] = *(const bf16x8*)&As[swz64(wr * 64 + i * 16 + l15, ks * 32 + l4 * 8)];
      #pragma unroll
      for (int i = 0; i < 4; ++i)
        bfr[i] = *(const bf16x8*)&Bs[swz64(wc * 64 + i * 16 + l15, ks * 32 + l4 * 8)];
      #pragma unroll
      for (int mi = 0; mi < 4; ++mi)
        #pragma unroll
        for (int ni = 0; ni < 4; ++ni)
          acc[mi][ni] = __builtin_amdgcn_mfma_f32_16x16x32_bf16(
              af[mi], bfr[ni], acc[mi][ni], 0, 0, 0);
    }
    __syncthreads();
  }
  #pragma unroll
  for (int mi = 0; mi < 4; ++mi) {
    #pragma unroll
    for (int r = 0; r < 4; ++r) {
      const int grow = row0 + wr * 64 + mi * 16 + l4 * 4 + r;
      if (grow < MROWS) {
        const int bb = grow / NTOK, n = grow - bb * NTOK;
        #pragma unroll
        for (int ni = 0; ni < 4; ++ni) {
          const int gc = col0 + wc * 64 + ni * 16 + l15;
          const int which = gc >> 9;
          const int col = gc & 511;
          const int hh = col >> 6, d = col & 63;
          const size_t off = (size_t)((bb * NH + hh) * NTOK + n) * DH + d;
          const float vv = acc[mi][ni][r];
          if (which == 0)      qb[off] = f2b(vv * QSCALE);
          else if (which == 1) kb[off] = f2b(vv);
          else                 vb[off] = f2b(vv);
        }
      }
    }
  }
}

// ============ MFMA GEMM 2: out = attn(bf16) @ W_out -> fp32 =================
__global__ __launch_bounds__(256) void k_out(
    const unsigned short* __restrict__ a,    // bf16 [MROWS][512]
    const unsigned short* __restrict__ wT,   // bf16 [512][512] (W_out^T)
    float* __restrict__ out)                 // fp32 [MROWS][512]
{
  __shared__ alignas(16) unsigned short As[128 * 64];
  __shared__ alignas(16) unsigned short Bs[128 * 64];
  const int lid = xcdchunk(blockIdx.x, NBOUT);
  const int bm = lid / 4, bn = lid % 4;
  const int tid = threadIdx.x;
  const int lane = tid & 63, wid = tid >> 6;
  const int wr = wid >> 1, wc = wid & 1;
  const int row0 = bm * 128, col0 = bn * 128;
  const int l15 = lane & 15, l4 = lane >> 4;
  const int lr = lane >> 3;
  const int srcChunk = (lane & 7) ^ lr;

  const unsigned short* aRow[4];
  const unsigned short* bRow[4];
  #pragma unroll
  for (int j = 0; j < 4; ++j) {
    int gr = row0 + wid * 32 + j * 8 + lr;
    if (gr >= MROWS) gr = MROWS - 1;
    aRow[j] = a + (size_t)gr * 512 + srcChunk * 8;
    bRow[j] = wT + (size_t)(col0 + wid * 32 + j * 8 + lr) * 512 + srcChunk * 8;
  }

  f32x4 acc[4][4];
  #pragma unroll
  for (int i = 0; i < 4; ++i)
    #pragma unroll
    for (int j = 0; j < 4; ++j) acc[i][j] = f32x4{0.f, 0.f, 0.f, 0.f};

  for (int kt = 0; kt < 512; kt += 64) {
    #pragma unroll
    for (int j = 0; j < 4; ++j) {
      gload16(aRow[j] + kt, &As[(wid * 32 + j * 8) * 64]);
      gload16(bRow[j] + kt, &Bs[(wid * 32 + j * 8) * 64]);
    }
    __syncthreads();
    #pragma unroll
    for (int ks = 0; ks < 2; ++ks) {
      bf16x8 af[4], bfr[4];
      #pragma unroll
      for (int i = 0; i < 4; ++i)
        af[i] = *(const bf16x8*)&As[swz64(wr * 64 + i * 16 + l15, ks * 32 + l4 * 8)];
      #pragma unroll
      for (int i = 0; i < 4; ++i)
        bfr[i] = *(const bf16x8*)&Bs[swz64(wc * 64 + i * 16 + l15, ks * 32 + l4 * 8)];
      #pragma unroll
      for (int mi = 0; mi < 4; ++mi)
        #pragma unroll
        for (int ni = 0; ni < 4; ++ni)
          acc[mi][ni] = __builtin_amdgcn_mfma_f32_16x16x32_bf16(
              af[mi], bfr[ni], acc[mi][ni], 0, 0, 0);
    }
    __syncthreads();
  }
  #pragma unroll
  for (int mi = 0; mi < 4; ++mi) {
    #pragma unroll
    for (int r = 0; r < 4; ++r) {
      const int grow = row0 + wr * 64 + mi * 16 + l4 * 4 + r;
      if (grow < MROWS) {
        #pragma unroll
        for (int ni = 0; ni < 4; ++ni) {
          const int gc = col0 + wc * 64 + ni * 16 + l15;
          out[(size_t)grow * 512 + gc] = acc[mi][ni][r];
        }
      }
    }
  }
}

// ---------------- cls attention, parallel 3-stage ---------------------------
__global__ __launch_bounds__(256) void k_cls1(
    const unsigned short* __restrict__ qb, const unsigned short* __restrict__ kb,
    float* __restrict__ simb, float* __restrict__ cmax)
{
  __shared__ float qv[64];
  __shared__ float sred[4];
  const int bh = blockIdx.x, ch = blockIdx.y, tid = threadIdx.x;
  if (tid < 64) qv[tid] = b2f(qb[(size_t)bh * NTOK * 64 + tid]);
  __syncthreads();
  const int j = ch * 256 + tid;
  float dot = -3e38f;
  if (j < NTOK) {
    const unsigned short* kr = kb + (size_t)bh * NTOK * 64 + (size_t)j * 64;
    dot = 0.f;
    #pragma unroll
    for (int d0 = 0; d0 < 64; d0 += 8) {
      const bf16x8 kv = *(const bf16x8*)(kr + d0);
      #pragma unroll
      for (int j2 = 0; j2 < 8; ++j2) dot += qv[d0 + j2] * (float)kv[j2];
    }
    simb[bh * 3200 + j] = dot;
  }
  float lm = dot;
  #pragma unroll
  for (int off = 32; off; off >>= 1) lm = fmaxf(lm, __shfl_xor(lm, off));
  if ((tid & 63) == 0) sred[tid >> 6] = lm;
  __syncthreads();
  if (tid == 0)
    cmax[bh * NCH + ch] = fmaxf(fmaxf(sred[0], sred[1]), fmaxf(sred[2], sred[3]));
}

__global__ __launch_bounds__(256) void k_cls2(
    const unsigned short* __restrict__ vb, const float* __restrict__ simb,
    const float* __restrict__ cmax, float* __restrict__ pacc,
    float* __restrict__ psum)
{
  __shared__ float pa[4][64];
  __shared__ float pw[4];
  const int bh = blockIdx.x, ch = blockIdx.y, tid = threadIdx.x;
  const int wave = tid >> 6, d = tid & 63;
  float mx = -3e38f;
  #pragma unroll
  for (int i = 0; i < NCH; ++i) mx = fmaxf(mx, cmax[bh * NCH + i]);
  float acc = 0.f, ps = 0.f;
  const int j0 = ch * 256 + wave * 64;
  for (int i = 0; i < 64; ++i) {
    const int j = j0 + i;
    if (j < NTOK) {
      const float p = __expf(simb[bh * 3200 + j] - mx);
      acc += p * b2f(vb[(size_t)bh * NTOK * 64 + (size_t)j * 64 + d]);
      ps += p;
    }
  }
  pa[wave][d] = acc;
  if (d == 0) pw[wave] = ps;
  __syncthreads();
  if (tid < 64)
    pacc[((size_t)bh * NCH + ch) * 64 + tid] = pa[0][tid] + pa[1][tid] + pa[2][tid] + pa[3][tid];
  if (tid == 0)
    psum[bh * NCH + ch] = pw[0] + pw[1] + pw[2] + pw[3];
}

__global__ __launch_bounds__(64) void k_cls3(
    const float* __restrict__ pacc, const float* __restrict__ psum,
    unsigned short* __restrict__ attnb)
{
  const int bh = blockIdx.x, d = threadIdx.x;
  float a = 0.f, s = 0.f;
  #pragma unroll
  for (int ch = 0; ch < NCH; ++ch) {
    a += pacc[((size_t)bh * NCH + ch) * 64 + d];
    s += psum[bh * NCH + ch];
  }
  const int bb = bh >> 3, hh = bh & 7;
  attnb[((size_t)bb * NTOK + 0) * 512 + hh * 64 + d] = f2b(a / s);
}

// -------- MFMA global key-projection max (4x64 rows/block, atomic) ----------
__global__ __launch_bounds__(256) void k_keymax(
    const unsigned short* __restrict__ kb, const unsigned short* __restrict__ projb,
    u32* __restrict__ gmaxu)
{
  __shared__ alignas(16) unsigned short projL[MPK * 64];
  __shared__ float red[4];
  const int blk = blockIdx.x, tid = threadIdx.x;
  const int lane = tid & 63, wave = tid >> 6;
  const int l15 = lane & 15, l4 = lane >> 4;
  const int mw0 = wave * 80;
  {
    const char* srcb = (const char*)projb;
    char* dstb = (char*)projL;
    #pragma unroll
    for (int j = 0; j < 10; ++j) {
      const int off = (j * 4 + wave) * 1024;
      gload16(srcb + off + lane * 16, dstb + off);
    }
  }
  __syncthreads();
  float lm = -3e38f;
  for (int rg = 0; rg < 4; ++rg) {
    const int row0 = (blk * 4 + rg) * 64;
    if (row0 >= NROWS) break;
    bf16x8 bfrag[4][2];
    #pragma unroll
    for (int tf = 0; tf < 4; ++tf) {
      int gr = row0 + tf * 16 + l15;
      if (gr >= NROWS) gr = NROWS - 1;
      #pragma unroll
      for (int ks = 0; ks < 2; ++ks)
        bfrag[tf][ks] = *(const bf16x8*)(kb + (size_t)gr * 64 + ks * 32 + l4 * 8);
    }
    f32x4 acc[5][4];
    #pragma unroll
    for (int i = 0; i < 5; ++i)
      #pragma unroll
      for (int j = 0; j < 4; ++j) acc[i][j] = f32x4{0.f, 0.f, 0.f, 0.f};
    #pragma unroll
    for (int mf = 0; mf < 5; ++mf) {
      const bf16x8 a0 = *(const bf16x8*)&projL[swz64(mw0 + mf * 16 + l15, l4 * 8)];
      const bf16x8 a1 = *(const bf16x8*)&projL[swz64(mw0 + mf * 16 + l15, 32 + l4 * 8)];
      #pragma unroll
      for (int tf = 0; tf < 4; ++tf) {
        acc[mf][tf] = __builtin_amdgcn_mfma_f32_16x16x32_bf16(a0, bfrag[tf][0], acc[mf][tf], 0, 0, 0);
        acc[mf][tf] = __builtin_amdgcn_mfma_f32_16x16x32_bf16(a1, bfrag[tf][1], acc[mf][tf], 0, 0, 0);
      }
    }
    #pragma unroll
    for (int tf = 0; tf < 4; ++tf) {
      const bool colok = (row0 + tf * 16 + l15) < NROWS;
      #pragma unroll
      for (int mf = 0; mf < 5; ++mf)
        #pragma unroll
        for (int r = 0; r < 4; ++r) {
          const int m = mw0 + mf * 16 + l4 * 4 + r;
          if (colok && m < MF) lm = fmaxf(lm, DN * acc[mf][tf][r]);
        }
    }
  }
  #pragma unroll
  for (int off = 32; off; off >>= 1) lm = fmaxf(lm, __shfl_xor(lm, off));
  if (lane == 0) red[wave] = lm;
  __syncthreads();
  if (tid == 0) {
    const float bm = fmaxf(fmaxf(red[0], red[1]), fmaxf(red[2], red[3]));
    atomicMax(gmaxu, fenc(bm));
  }
}

// ======== fused linear attention: ctx phase + qry phase, one block/group ====
// r29 = r27 + ONLY diag parallelized across all 8 waves (1 load/lane +
// 3-step shfl_xor tree).  K stays loaded at point-of-use in computef
// (r28's register "prefetch" was rematerialized by the compiler -> extra
// FETCH pass; reverted).
__global__ __launch_bounds__(512) void k_lin(
    const unsigned short* __restrict__ kb, const unsigned short* __restrict__ vb,
    const unsigned short* __restrict__ qb, const unsigned short* __restrict__ projb,
    const u32* __restrict__ gmaxu, unsigned short* __restrict__ attnb)
{
  __shared__ alignas(16) unsigned short smAB[2 * 64 * 320];  // 80 KB aliased region
  __shared__ alignas(16) unsigned short ctxL[64 * 320];      // 40 KB ctx swz320 image
  __shared__ float diagA[2][64];
  __shared__ float diagB[2][64];
  __shared__ float rmax_l[2][8][64];
  __shared__ float dnm_l[2][8][64];

  unsigned short* const kpT = smAB;                   // [MC*64] swz64
  unsigned short* const vTb = smAB + MC * 64;         // [2][64*64] swz64 dbuf

  const int g = blockIdx.x, bh = g >> 4, c = g & 15;
  const int bb = bh >> 3, hh = bh & 7;
  const int tid = threadIdx.x;
  const int lane = tid & 63, wave = tid >> 6;
  const int l15 = lane & 15, l4 = lane >> 4;
  const int nf = (wave < 2) ? 3 : 2;
  const int M0 = (wave < 2) ? wave * 48 : 96 + (wave - 2) * 32;
  const float gm = fdec(*gmaxu);

  bf16x8 pfr[3][2];  // shared by both phases (same wave->m mapping)
  #pragma unroll
  for (int mf = 0; mf < 3; ++mf)
    #pragma unroll
    for (int ks = 0; ks < 2; ++ks)
      pfr[mf][ks] = (mf < nf)
          ? *(const bf16x8*)&projb[swz64(M0 + mf * 16 + l15, ks * 32 + l4 * 8)]
          : bf16x8{0, 0, 0, 0, 0, 0, 0, 0};

  const unsigned short* ksrc = kb + (size_t)bh * NTOK * 64;
  const unsigned short* vsrc = vb + (size_t)bh * NTOK * 64;
  const unsigned short* qsrc = qb + (size_t)bh * NTOK * 64;

  // ===================== phase A: context =====================
  f32x4 ctxacc[3][4];
  #pragma unroll
  for (int i = 0; i < 3; ++i)
    #pragma unroll
    for (int j = 0; j < 4; ++j) ctxacc[i][j] = f32x4{0.f, 0.f, 0.f, 0.f};
  float ksump[3][4];
  #pragma unroll
  for (int i = 0; i < 3; ++i)
    #pragma unroll
    for (int j = 0; j < 4; ++j) ksump[i][j] = 0.f;

  auto stagevd = [&](int kt, int buf) {
    {  // vT staging (all threads)
      const int t = tid & 63, dblk = (tid >> 6) & 7;
      const int n = kt * 64 + t;
      unsigned short* vT = vTb + buf * 4096;
      if (n < 197) {
        const int node = (n == 0) ? 0 : 1 + c * 196 + (n - 1);
        const ushort8 v = *(const ushort8*)(vsrc + (size_t)node * 64 + dblk * 8);
        #pragma unroll
        for (int j = 0; j < 8; ++j) vT[swz64(dblk * 8 + j, t)] = v[j];
      } else {
        #pragma unroll
        for (int j = 0; j < 8; ++j) vT[swz64(dblk * 8 + j, t)] = 0;
      }
    }
    {  // diag parallel: wave w rows 8w..8w+7, lane chunk lane&7
      const int row = wave * 8 + (lane >> 3);
      const int n = kt * 64 + row;
      const int nn = (n < 197) ? n : 0;
      const int node = (nn == 0) ? 0 : 1 + c * 196 + (nn - 1);
      const bf16x8 v = *(const bf16x8*)(ksrc + (size_t)node * 64 + (lane & 7) * 8);
      float s = 0.f;
      #pragma unroll
      for (int j = 0; j < 8; ++j) { const float f = (float)v[j]; s += f * f; }
      s += __shfl_xor(s, 1); s += __shfl_xor(s, 2); s += __shfl_xor(s, 4);
      if ((lane & 7) == 0) diagA[buf][row] = HDN2 * s;
    }
  };
  // stage1 + stage2 for tile kt reading buffer buf (K at point of use)
  auto computef = [&](int kt, int buf) {
    #pragma unroll
    for (int tf = 0; tf < 4; ++tf) {
      const int n = kt * 64 + tf * 16 + l15;
      const int nn = (n < 197) ? n : 0;
      const int node = (nn == 0) ? 0 : 1 + c * 196 + (nn - 1);
      bf16x8 b0 = *(const bf16x8*)(ksrc + (size_t)node * 64 + l4 * 8);
      bf16x8 b1 = *(const bf16x8*)(ksrc + (size_t)node * 64 + 32 + l4 * 8);
      f32x4 a1[3];
      #pragma unroll
      for (int mf = 0; mf < 3; ++mf) {
        a1[mf] = f32x4{0.f, 0.f, 0.f, 0.f};
        if (mf < nf) {
          a1[mf] = __builtin_amdgcn_mfma_f32_16x16x32_bf16(pfr[mf][0], b0, a1[mf], 0, 0, 0);
          a1[mf] = __builtin_amdgcn_mfma_f32_16x16x32_bf16(pfr[mf][1], b1, a1[mf], 0, 0, 0);
        }
      }
      const int t = tf * 16 + l15;
      const int nv = kt * 64 + t;
      const float dg = diagA[buf][t];
      #pragma unroll
      for (int mf = 0; mf < 3; ++mf) {
        if (mf < nf) {
          #pragma unroll
          for (int r = 0; r < 4; ++r) {
            const int m = M0 + mf * 16 + l4 * 4 + r;
            float kp = 0.f;
            if (m < MF && nv < 197)
              kp = RATIO * (__expf(DN * a1[mf][r] - dg - gm) + EPSV);
            ksump[mf][r] += kp;
            kpT[swz64(m, t)] = f2b(kp);
          }
        }
      }
    }
    // stage 2: ctx += KP_T . vT (intra-wave kpT dependency only)
    #pragma unroll
    for (int ks = 0; ks < 2; ++ks) {
      bf16x8 a2[3];
      #pragma unroll
      for (int mf = 0; mf < 3; ++mf)
        if (mf < nf)
          a2[mf] = *(const bf16x8*)&kpT[swz64(M0 + mf * 16 + l15, ks * 32 + l4 * 8)];
      const unsigned short* vT = vTb + buf * 4096;
      #pragma unroll
      for (int df = 0; df < 4; ++df) {
        const bf16x8 b2 = *(const bf16x8*)&vT[swz64(df * 16 + l15, ks * 32 + l4 * 8)];
        #pragma unroll
        for (int mf = 0; mf < 3; ++mf)
          if (mf < nf)
            ctxacc[mf][df] = __builtin_amdgcn_mfma_f32_16x16x32_bf16(a2[mf], b2, ctxacc[mf][df], 0, 0, 0);
      }
    }
  };

  // pipelined schedule: 5 barriers (r27 form)
  stagevd(0, 0);
  __syncthreads();
  for (int kt = 0; kt < 4; ++kt) {
    const int b = kt & 1;
    if (kt < 3) stagevd(kt + 1, b ^ 1);   // overlap next-tile staging
    computef(kt, b);
    __syncthreads();                      // vT/diag(kt+1) visible; vT[b] reads done
  }

  // ksum butterfly: after 4 xor steps ALL lanes in the l15-group hold the sum;
  // (wave,l4,r)->m mapping matches phase B's ksr exactly -> registers only.
  float ksr[3][4];
  #pragma unroll
  for (int mf = 0; mf < 3; ++mf) {
    #pragma unroll
    for (int r = 0; r < 4; ++r) {
      float v = ksump[mf][r];
      v += __shfl_xor(v, 1); v += __shfl_xor(v, 2);
      v += __shfl_xor(v, 4); v += __shfl_xor(v, 8);
      ksr[mf][r] = v;
    }
  }
  // ctx -> ctxL (same swz320 image layout the global write used)
  #pragma unroll
  for (int mf = 0; mf < 3; ++mf) {
    if (mf < nf) {
      #pragma unroll
      for (int df = 0; df < 4; ++df) {
        const int d = df * 16 + l15;
        const int m = M0 + mf * 16 + l4 * 4;
        uint2 u;
        u.x = pk2(ctxacc[mf][df][0], ctxacc[mf][df][1]);
        u.y = pk2(ctxacc[mf][df][2], ctxacc[mf][df][3]);
        *(uint2*)&ctxL[swz320(d, m)] = u;
      }
    }
  }
  __syncthreads();   // ctxL visible; all phase-A LDS reads complete

  // ===================== phase B: query (r23 schedule) =====================
  const int tf4 = wave & 3, dfh = wave >> 2;

  auto diagf = [&](int qt, int buf) {
    // diag parallel: wave w rows 8w..8w+7, lane chunk lane&7
    const int row = wave * 8 + (lane >> 3);
    const int n = qt * 64 + row;
    const int nn = (n < 196) ? n : 0;
    const int node = 1 + c * 196 + nn;
    const bf16x8 v = *(const bf16x8*)(qsrc + (size_t)node * 64 + (lane & 7) * 8);
    float s = 0.f;
    #pragma unroll
    for (int j = 0; j < 8; ++j) { const float f = (float)v[j]; s += f * f; }
    s += __shfl_xor(s, 1); s += __shfl_xor(s, 2); s += __shfl_xor(s, 4);
    if ((lane & 7) == 0) diagB[buf][row] = HDN2 * s;
  };
  auto stage3f = [&](int qt, int buf, f32x4 (&acc3)[3][4]) {
    #pragma unroll
    for (int i = 0; i < 3; ++i)
      #pragma unroll
      for (int j = 0; j < 4; ++j) acc3[i][j] = f32x4{0.f, 0.f, 0.f, 0.f};
    #pragma unroll
    for (int tf = 0; tf < 4; ++tf) {
      const int n = qt * 64 + tf * 16 + l15;
      const int nn = (n < 196) ? n : 0;
      const int node = 1 + c * 196 + nn;
      bf16x8 b0 = *(const bf16x8*)(qsrc + (size_t)node * 64 + l4 * 8);
      bf16x8 b1 = *(const bf16x8*)(qsrc + (size_t)node * 64 + 32 + l4 * 8);
      #pragma unroll
      for (int mf = 0; mf < 3; ++mf) {
        if (mf < nf) {
          acc3[mf][tf] = __builtin_amdgcn_mfma_f32_16x16x32_bf16(pfr[mf][0], b0, acc3[mf][tf], 0, 0, 0);
          acc3[mf][tf] = __builtin_amdgcn_mfma_f32_16x16x32_bf16(pfr[mf][1], b1, acc3[mf][tf], 0, 0, 0);
        }
      }
    }
    #pragma unroll
    for (int tf = 0; tf < 4; ++tf) {
      float v = -3e38f;
      #pragma unroll
      for (int mf = 0; mf < 3; ++mf)
        if (mf < nf)
          #pragma unroll
          for (int r = 0; r < 4; ++r) {
            const int m = M0 + mf * 16 + l4 * 4 + r;
            if (m < MF) v = fmaxf(v, DN * acc3[mf][tf][r]);
          }
      v = fmaxf(v, __shfl_xor(v, 16));
      v = fmaxf(v, __shfl_xor(v, 32));
      if (l4 == 0) rmax_l[buf][wave][tf * 16 + l15] = v;
    }
  };
  auto qpwritef = [&](int qt, int buf, const f32x4 (&acc3)[3][4]) {
    unsigned short* qp = smAB + buf * (64 * 320);
    #pragma unroll
    for (int tf = 0; tf < 4; ++tf) {
      const int t = tf * 16 + l15;
      const int tq = qt * 64 + t;
      float rm = fmaxf(fmaxf(rmax_l[buf][0][t], rmax_l[buf][1][t]),
                       fmaxf(rmax_l[buf][2][t], rmax_l[buf][3][t]));
      rm = fmaxf(rm, fmaxf(fmaxf(rmax_l[buf][4][t], rmax_l[buf][5][t]),
                           fmaxf(rmax_l[buf][6][t], rmax_l[buf][7][t])));
      const float dg = diagB[buf][t];
      float dpart = 0.f;
      #pragma unroll
      for (int mf = 0; mf < 3; ++mf) {
        if (mf < nf) {
          float e[4];
          #pragma unroll
          for (int r = 0; r < 4; ++r) {
            const int m = M0 + mf * 16 + l4 * 4 + r;
            e[r] = (m < MF && tq < 196)
                 ? RATIO * (__expf(DN * acc3[mf][tf][r] - dg - rm) + EPSV) : 0.f;
            dpart += e[r] * ksr[mf][r];
          }
          uint2 u; u.x = pk2(e[0], e[1]); u.y = pk2(e[2], e[3]);
          *(uint2*)&qp[swz320(t, M0 + mf * 16 + l4 * 4)] = u;
        }
      }
      dpart += __shfl_xor(dpart, 16);
      dpart += __shfl_xor(dpart, 32);
      if (l4 == 0) dnm_l[buf][wave][t] = dpart;
    }
  };
  auto stage4f = [&](int qt, int buf) {
    const unsigned short* qp = smAB + buf * (64 * 320);
    f32x4 oacc[2];
    oacc[0] = f32x4{0.f, 0.f, 0.f, 0.f};
    oacc[1] = f32x4{0.f, 0.f, 0.f, 0.f};
    #pragma unroll
    for (int ks = 0; ks < 9; ++ks) {
      const bf16x8 a4 = *(const bf16x8*)&qp[swz320(tf4 * 16 + l15, ks * 32 + l4 * 8)];
      #pragma unroll
      for (int di = 0; di < 2; ++di) {
        const int d = dfh * 32 + di * 16 + l15;
        const bf16x8 b4 = *(const bf16x8*)&ctxL[swz320(d, ks * 32 + l4 * 8)];
        oacc[di] = __builtin_amdgcn_mfma_f32_16x16x32_bf16(a4, b4, oacc[di], 0, 0, 0);
      }
    }
    #pragma unroll
    for (int r = 0; r < 4; ++r) {
      const int tl = tf4 * 16 + l4 * 4 + r;
      const int tq = qt * 64 + tl;
      if (tq < 196) {
        float denom = 0.f;
        #pragma unroll
        for (int w8 = 0; w8 < 8; ++w8) denom += dnm_l[buf][w8][tl];
        const float dinv = 1.0f / denom;
        const int node = 1 + c * 196 + tq;
        unsigned short* orow = attnb + ((size_t)bb * NTOK + node) * 512 + hh * 64 + dfh * 32;
        #pragma unroll
        for (int di = 0; di < 2; ++di)
          orow[di * 16 + l15] = f2b(oacc[di][r] * dinv);
      }
    }
  };

  f32x4 acc3[3][4];
  diagf(0, 0);
  stage3f(0, 0, acc3);
  __syncthreads();             // rmax(0)+diag(0) visible
  qpwritef(0, 0, acc3);        // first qp write: >=2 barriers after last kpT/vT read
  for (int qt = 1; qt < 4; ++qt) {
    const int b = qt & 1, pb = b ^ 1;
    __syncthreads();           // qp(qt-1)+dnm(qt-1) visible
    diagf(qt, b);
    stage4f(qt - 1, pb);       // reads qp[pb]/dnm[pb]/ctxL
    stage3f(qt, b, acc3);      // writes rmax[b]
    __syncthreads();           // rmax(qt)+diag(qt) visible; stage4 reads done
    qpwritef(qt, b, acc3);     // writes qp[b]/dnm[b]
  }
  __syncthreads();             // qp(3)+dnm(3) visible
  stage4f(3, 1);
}

}  // namespace

extern "C" void kernel_launch(void* const* d_in, const int* in_sizes, int n_in,
                              void* d_out, int out_size, void* d_ws, size_t ws_size,
                              hipStream_t stream) {
  (void)in_sizes; (void)n_in; (void)out_size; (void)ws_size;
  const float* x    = (const float*)d_in[0];
  const float* wqkv = (const float*)d_in[1];
  const float* wout = (const float*)d_in[2];
  const float* proj = (const float*)d_in[3];
  float* out = (float*)d_out;

  const size_t QKV = (size_t)BH * NTOK * DH;  // 12,849,152 elements
  unsigned short* qb    = (unsigned short*)d_ws;
  unsigned short* kb    = qb + QKV;
  unsigned short* vb    = kb + QKV;
  unsigned short* attnb = vb + QKV;
  float* fbase = (float*)(attnb + QKV);
  u32*   gmaxu = (u32*)(fbase + 4096);        // 1 (encoded float)
  float* simb = fbase + 8192;                 // 64*3200
  float* cmax = simb + 64 * 3200;             // 64*13 (padded 1024)
  float* pacc = cmax + 1024;                  // 64*13*64
  float* psum = pacc + 64 * NCH * 64;         // 64*13 (padded 1024)
  unsigned short* wqkvT = (unsigned short*)(psum + 1024);  // bf16 [1536][512]
  unsigned short* woutT = wqkvT + 1536 * 512;              // bf16 [512][512]
  unsigned short* projb = woutT + 512 * 512;               // bf16 [320][64] swz image
  unsigned short* xb = attnb;  // xb aliases attnb (dead before attnb writes)

  const dim3 blk(256);
  k_projb  <<<dim3(10),       blk, 0, stream>>>(proj, projb, gmaxu);
  k_tconv  <<<dim3(24, 8),    blk, 0, stream>>>(wqkv, wqkvT, 512, 1536);
  k_tconv  <<<dim3(8, 8),     blk, 0, stream>>>(wout, woutT, 512, 512);
  k_cvt    <<<dim3((int)(QKV / 8 + 255) / 256), blk, 0, stream>>>(x, xb, (int)(QKV / 8));
  k_qkv    <<<dim3(NBQKV),    blk, 0, stream>>>(xb, wqkvT, qb, kb, vb);
  k_cls1   <<<dim3(BH, NCH),  blk, 0, stream>>>(qb, kb, simb, cmax);
  k_cls2   <<<dim3(BH, NCH),  blk, 0, stream>>>(vb, simb, cmax, pacc, psum);
  k_cls3   <<<dim3(BH), dim3(64), 0, stream>>>(pacc, psum, attnb);
  k_keymax <<<dim3(NMAXB),    blk, 0, stream>>>(kb, projb, gmaxu);
  k_lin    <<<dim3(1024), dim3(512), 0, stream>>>(kb, vb, qb, projb, gmaxu, attnb);
  k_out    <<<dim3(NBOUT),    blk, 0, stream>>>(attnb, woutT, out);
}